// Round 2
// baseline (4201.393 us; speedup 1.0000x reference)
//
#include <hip/hip_runtime.h>

// Residual VQ: x [B,N,D] fp32, codebooks [Q,C,D] fp32
// Outputs (flat fp32 in d_out): qout [B*N*D], indices [B*N*Q] (as float), losses [Q]
constexpr int Bq = 8;
constexpr int Nn = 4096;
constexpr int Dd = 256;
constexpr int Qq = 8;
constexpr int Cc = 1024;
constexpr int Mm = Bq * Nn;      // 32768 tokens
constexpr int TT = 16;           // tokens per block
constexpr int WW = 4;            // codewords per thread (1 pass: 256*4 = 1024)
constexpr int NT = 256;          // threads per block

// ---------------------------------------------------------------------------
// prep: cnorm[q*C+c] = sum_d cb[q][c][d]^2 ; zero loss accumulators
__global__ void prep_kernel(const float* __restrict__ cbs,
                            float* __restrict__ cnorm,
                            float* __restrict__ loss_acc) {
  const int wave = threadIdx.x >> 6;
  const int lane = threadIdx.x & 63;
  const int row  = blockIdx.x * 4 + wave;            // 0 .. Q*C-1
  const float4* r4 = reinterpret_cast<const float4*>(cbs + (size_t)row * Dd);
  const float4 v = r4[lane];                          // 64 lanes x float4 = 256
  float s = v.x * v.x + v.y * v.y + v.z * v.z + v.w * v.w;
#pragma unroll
  for (int off = 32; off; off >>= 1) s += __shfl_down(s, off);
  if (lane == 0) cnorm[row] = s;
  if (blockIdx.x == 0 && threadIdx.x < Qq) loss_acc[threadIdx.x] = 0.0f;
}

// ---------------------------------------------------------------------------
// one VQ stage, fully fused: distances + argmin + gather + residual/qout/loss
// grid: Mm/TT blocks of NT threads
__global__ __launch_bounds__(NT)
void vq_stage(const float* __restrict__ cb,      // [C][D] this stage
              const float* __restrict__ cnorm,   // [C]   this stage
              const float* __restrict__ rin,     // [M][D] residual in
              float* __restrict__ rout,          // [M][D] residual out
              float* __restrict__ qout,          // [M][D] accumulated quantized
              float* __restrict__ idx_out,       // [M][Q] indices as float
              float* __restrict__ loss_acc,      // [Q] loss sums
              int q) {
  __shared__ float4 rs[TT][Dd / 4];               // 16 KB residual tile
  __shared__ float red_v[4][TT];
  __shared__ int   red_i[4][TT];
  __shared__ int   win[TT];

  const int tid  = threadIdx.x;
  const int tok0 = blockIdx.x * TT;

  // stage residual tile: TT*D floats = 1024 float4; 4 per thread, coalesced
  {
    const float4* src = reinterpret_cast<const float4*>(rin + (size_t)tok0 * Dd);
    float4* dst = &rs[0][0];
#pragma unroll
    for (int k = 0; k < (TT * Dd / 4) / NT; ++k) dst[tid + k * NT] = src[tid + k * NT];
  }
  __syncthreads();

  // thread owns codewords c_w = w*256 + tid, w=0..3 (ascending -> strict-less
  // keeps lowest index on ties, matching numpy argmin)
  const float4* cw[WW];
#pragma unroll
  for (int w = 0; w < WW; ++w)
    cw[w] = reinterpret_cast<const float4*>(cb + (size_t)(w * NT + tid) * Dd);

  float acc[WW][TT];
#pragma unroll
  for (int w = 0; w < WW; ++w)
#pragma unroll
    for (int m = 0; m < TT; ++m) acc[w][m] = 0.0f;

  // software-pipelined codeword chunks (double-buffered in regs)
  float4 a[WW], nx[WW];
#pragma unroll
  for (int w = 0; w < WW; ++w) a[w] = cw[w][0];

#pragma unroll 1
  for (int d4 = 0; d4 < Dd / 4; ++d4) {
    if (d4 + 1 < Dd / 4) {
#pragma unroll
      for (int w = 0; w < WW; ++w) nx[w] = cw[w][d4 + 1];
    }
#pragma unroll
    for (int m = 0; m < TT; ++m) {
      const float4 r = rs[m][d4];                       // LDS broadcast
#pragma unroll
      for (int w = 0; w < WW; ++w) {
        acc[w][m] += r.x * a[w].x;
        acc[w][m] += r.y * a[w].y;
        acc[w][m] += r.z * a[w].z;
        acc[w][m] += r.w * a[w].w;
      }
    }
#pragma unroll
    for (int w = 0; w < WW; ++w) a[w] = nx[w];
  }

  // NOTE: the FMA chain above accumulates x,y,z,w sequentially per d4, in
  // ascending d4 order, from 0.0f — bitwise-identical to the round-1 kernel
  // that matched numpy argmin exactly.  Do not reorder.
  float cn[WW];
#pragma unroll
  for (int w = 0; w < WW; ++w) cn[w] = cnorm[w * NT + tid];

  float minv[TT];
  int   mini[TT];
#pragma unroll
  for (int m = 0; m < TT; ++m) {
    float v = 3.4e38f;
    int   i = 0;
#pragma unroll
    for (int w = 0; w < WW; ++w) {               // ascending codeword index
      const float s = cn[w] - 2.0f * acc[w][m];
      if (s < v) { v = s; i = w * NT + tid; }
    }
    minv[m] = v;
    mini[m] = i;
  }

  // wave argmin reduce (value, then lowest index on exact ties)
#pragma unroll
  for (int m = 0; m < TT; ++m) {
    float v = minv[m];
    int   i = mini[m];
#pragma unroll
    for (int s = 32; s; s >>= 1) {
      const float ov = __shfl_xor(v, s);
      const int   oi = __shfl_xor(i, s);
      if (ov < v || (ov == v && oi < i)) { v = ov; i = oi; }
    }
    minv[m] = v;
    mini[m] = i;
  }
  const int lane = tid & 63;
  const int wv   = tid >> 6;
  if (lane == 0) {
#pragma unroll
    for (int m = 0; m < TT; ++m) { red_v[wv][m] = minv[m]; red_i[wv][m] = mini[m]; }
  }
  __syncthreads();
  if (tid < TT) {
    float v = red_v[0][tid];
    int   i = red_i[0][tid];
#pragma unroll
    for (int w = 1; w < 4; ++w) {
      const float ov = red_v[w][tid];
      const int   oi = red_i[w][tid];
      if (ov < v || (ov == v && oi < i)) { v = ov; i = oi; }
    }
    win[tid] = i;
    idx_out[(size_t)(tok0 + tid) * Qq + q] = (float)i;   // indices as float
  }
  __syncthreads();

  // epilogue: gather winner codeword, loss, residual & qout update.
  //   e = q - r; q_st = r + e; r_new = r - q_st; qout += q_st; loss += e^2
  float lsum = 0.0f;
  {
    const float4* cb4   = reinterpret_cast<const float4*>(cb);
    float4* routp = reinterpret_cast<float4*>(rout + (size_t)tok0 * Dd);
    float4* qoutp = reinterpret_cast<float4*>(qout + (size_t)tok0 * Dd);
#pragma unroll
    for (int k = 0; k < (TT * Dd / 4) / NT; ++k) {
      const int j  = tid + k * NT;
      const int m  = j >> 6;        // wave-uniform token
      const int d4 = j & 63;
      const int widx = win[m];
      const float4 cv = cb4[(size_t)widx * (Dd / 4) + d4];
      const float4 rv = rs[m][d4];
      const float ex = cv.x - rv.x, ey = cv.y - rv.y, ez = cv.z - rv.z, ew = cv.w - rv.w;
      const float qsx = rv.x + ex, qsy = rv.y + ey, qsz = rv.z + ez, qsw = rv.w + ew;
      lsum += ex * ex + ey * ey + ez * ez + ew * ew;
      routp[j] = make_float4(rv.x - qsx, rv.y - qsy, rv.z - qsz, rv.w - qsw);
      float4 qo;
      if (q == 0) {
        qo = make_float4(qsx, qsy, qsz, qsw);            // overwrite (no stale state)
      } else {
        const float4 old = qoutp[j];
        qo = make_float4(old.x + qsx, old.y + qsy, old.z + qsz, old.w + qsw);
      }
      qoutp[j] = qo;
    }
  }
#pragma unroll
  for (int s = 32; s; s >>= 1) lsum += __shfl_xor(lsum, s);
  if (lane == 0) atomicAdd(&loss_acc[q], lsum);
}

// ---------------------------------------------------------------------------
__global__ void finalize_losses(const float* __restrict__ loss_acc,
                                float* __restrict__ loss_out) {
  if (threadIdx.x < Qq) loss_out[threadIdx.x] = loss_acc[threadIdx.x] * (1.0f / (float)(Mm * Dd));
}

extern "C" void kernel_launch(void* const* d_in, const int* in_sizes, int n_in,
                              void* d_out, int out_size, void* d_ws, size_t ws_size,
                              hipStream_t stream) {
  const float* x   = (const float*)d_in[0];   // [B,N,D]
  const float* cbs = (const float*)d_in[1];   // [Q,C,D]
  float* out      = (float*)d_out;
  float* qout     = out;                               // M*D
  float* idx_out  = out + (size_t)Mm * Dd;             // M*Q
  float* loss_out = idx_out + (size_t)Mm * Qq;         // Q

  float* residual = (float*)d_ws;                      // M*D floats = 32 MB
  float* loss_acc = residual + (size_t)Mm * Dd;        // Q floats (pad 64)
  float* cnorm    = loss_acc + 64;                     // Q*C floats

  prep_kernel<<<(Qq * Cc) / 4, NT, 0, stream>>>(cbs, cnorm, loss_acc);

  for (int q = 0; q < Qq; ++q) {
    const float* rin = (q == 0) ? x : residual;
    vq_stage<<<Mm / TT, NT, 0, stream>>>(cbs + (size_t)q * Cc * Dd,
                                         cnorm + (size_t)q * Cc,
                                         rin, residual,
                                         qout, idx_out, loss_acc, q);
  }

  finalize_losses<<<1, 64, 0, stream>>>(loss_acc, loss_out);
}

// Round 3
// 2439.373 us; speedup vs baseline: 1.7223x; 1.7223x over previous
//
#include <hip/hip_runtime.h>

// Residual VQ: x [B,N,D] fp32, codebooks [Q,C,D] fp32
// Outputs (flat fp32 in d_out): qout [B*N*D], indices [B*N*Q] (as float), losses [Q]
constexpr int Bq = 8;
constexpr int Nn = 4096;
constexpr int Dd = 256;
constexpr int Qq = 8;
constexpr int Cc = 1024;
constexpr int Mm = Bq * Nn;      // 32768 tokens
constexpr int TT = 16;           // tokens per block
constexpr int WW = 4;            // codewords per thread (1 pass: 256*4 = 1024)
constexpr int NT = 256;          // threads per block

// ---------------------------------------------------------------------------
// prep: cnorm[q*C+c] = sum_d cb[q][c][d]^2 ; zero loss accumulators
__global__ void prep_kernel(const float* __restrict__ cbs,
                            float* __restrict__ cnorm,
                            float* __restrict__ loss_acc) {
  const int wave = threadIdx.x >> 6;
  const int lane = threadIdx.x & 63;
  const int row  = blockIdx.x * 4 + wave;            // 0 .. Q*C-1
  const float4* r4 = reinterpret_cast<const float4*>(cbs + (size_t)row * Dd);
  const float4 v = r4[lane];                          // 64 lanes x float4 = 256
  float s = v.x * v.x + v.y * v.y + v.z * v.z + v.w * v.w;
#pragma unroll
  for (int off = 32; off; off >>= 1) s += __shfl_down(s, off);
  if (lane == 0) cnorm[row] = s;
  if (blockIdx.x == 0 && threadIdx.x < Qq) loss_acc[threadIdx.x] = 0.0f;
}

// ---------------------------------------------------------------------------
// transpose codebooks: cbT[q][d4][c] = float4(cb[q][c][4*d4 .. 4*d4+3])
// so the vq_stage streaming loads are coalesced across threads (thread=codeword).
constexpr int TC = 64;   // codewords per block
constexpr int TD = 16;   // d4 chunk
__global__ __launch_bounds__(NT)
void transpose_cb(const float* __restrict__ cbs, float4* __restrict__ cbT) {
  __shared__ float4 tile[TC][TD + 1];
  const int q  = blockIdx.x / (Cc / TC);
  const int c0 = (blockIdx.x % (Cc / TC)) * TC;
  const float4* src = reinterpret_cast<const float4*>(cbs + ((size_t)q * Cc + c0) * Dd);
  const int tid = threadIdx.x;
#pragma unroll 1
  for (int d40 = 0; d40 < Dd / 4; d40 += TD) {
    // load TC rows x TD cols, coalesced within rows
#pragma unroll
    for (int it = 0; it < (TC * TD) / NT; ++it) {
      const int j = it * NT + tid;
      const int row = j / TD, col = j % TD;
      tile[row][col] = src[(size_t)row * (Dd / 4) + d40 + col];
    }
    __syncthreads();
    // store: consecutive threads -> consecutive codewords (coalesced)
#pragma unroll
    for (int it = 0; it < (TC * TD) / NT; ++it) {
      const int j = it * NT + tid;
      const int dd = j / TC, cc = j % TC;
      cbT[((size_t)q * (Dd / 4) + d40 + dd) * Cc + c0 + cc] = tile[cc][dd];
    }
    __syncthreads();
  }
}

// ---------------------------------------------------------------------------
// one VQ stage, fully fused: distances + argmin + gather + residual/qout/loss
// grid: Mm/TT blocks of NT threads
__global__ __launch_bounds__(NT)
void vq_stage(const float* __restrict__ cb,      // [C][D] this stage (row layout, epilogue gather)
              const float4* __restrict__ cbt,    // [D/4][C] this stage (transposed, streaming)
              const float* __restrict__ cnorm,   // [C]   this stage
              const float* __restrict__ rin,     // [M][D] residual in
              float* __restrict__ rout,          // [M][D] residual out
              float* __restrict__ qout,          // [M][D] accumulated quantized
              float* __restrict__ idx_out,       // [M][Q] indices as float
              float* __restrict__ loss_acc,      // [Q] loss sums
              int q) {
  __shared__ float4 rs[TT][Dd / 4];               // 16 KB residual tile
  __shared__ float red_v[4][TT];
  __shared__ int   red_i[4][TT];
  __shared__ int   win[TT];

  const int tid  = threadIdx.x;
  const int tok0 = blockIdx.x * TT;

  // stage residual tile: TT*D floats = 1024 float4; 4 per thread, coalesced
  {
    const float4* src = reinterpret_cast<const float4*>(rin + (size_t)tok0 * Dd);
    float4* dst = &rs[0][0];
#pragma unroll
    for (int k = 0; k < (TT * Dd / 4) / NT; ++k) dst[tid + k * NT] = src[tid + k * NT];
  }
  __syncthreads();

  float acc[WW][TT];
#pragma unroll
  for (int w = 0; w < WW; ++w)
#pragma unroll
    for (int m = 0; m < TT; ++m) acc[w][m] = 0.0f;

  // software-pipelined codeword chunks (double-buffered in regs), coalesced:
  // thread tid handles codewords w*256+tid; cbt[d4*C + c] is contiguous in c.
  float4 a[WW], nx[WW];
#pragma unroll
  for (int w = 0; w < WW; ++w) a[w] = cbt[w * NT + tid];

#pragma unroll 1
  for (int d4 = 0; d4 < Dd / 4; ++d4) {
    if (d4 + 1 < Dd / 4) {
      const float4* nxt = cbt + (size_t)(d4 + 1) * Cc;
#pragma unroll
      for (int w = 0; w < WW; ++w) nx[w] = nxt[w * NT + tid];
    }
#pragma unroll
    for (int m = 0; m < TT; ++m) {
      const float4 r = rs[m][d4];                       // LDS broadcast
#pragma unroll
      for (int w = 0; w < WW; ++w) {
        acc[w][m] += r.x * a[w].x;
        acc[w][m] += r.y * a[w].y;
        acc[w][m] += r.z * a[w].z;
        acc[w][m] += r.w * a[w].w;
      }
    }
#pragma unroll
    for (int w = 0; w < WW; ++w) a[w] = nx[w];
  }

  // NOTE: the FMA chain accumulates x,y,z,w sequentially per d4, ascending d4,
  // from 0.0f — bitwise-identical to the round-1 kernel that matched numpy
  // argmin exactly.  Do not reorder.
  float cn[WW];
#pragma unroll
  for (int w = 0; w < WW; ++w) cn[w] = cnorm[w * NT + tid];

  float minv[TT];
  int   mini[TT];
#pragma unroll
  for (int m = 0; m < TT; ++m) {
    float v = 3.4e38f;
    int   i = 0;
#pragma unroll
    for (int w = 0; w < WW; ++w) {               // ascending codeword index
      const float s = cn[w] - 2.0f * acc[w][m];
      if (s < v) { v = s; i = w * NT + tid; }
    }
    minv[m] = v;
    mini[m] = i;
  }

  // wave argmin reduce (value, then lowest index on exact ties)
#pragma unroll
  for (int m = 0; m < TT; ++m) {
    float v = minv[m];
    int   i = mini[m];
#pragma unroll
    for (int s = 32; s; s >>= 1) {
      const float ov = __shfl_xor(v, s);
      const int   oi = __shfl_xor(i, s);
      if (ov < v || (ov == v && oi < i)) { v = ov; i = oi; }
    }
    minv[m] = v;
    mini[m] = i;
  }
  const int lane = tid & 63;
  const int wv   = tid >> 6;
  if (lane == 0) {
#pragma unroll
    for (int m = 0; m < TT; ++m) { red_v[wv][m] = minv[m]; red_i[wv][m] = mini[m]; }
  }
  __syncthreads();
  if (tid < TT) {
    float v = red_v[0][tid];
    int   i = red_i[0][tid];
#pragma unroll
    for (int w = 1; w < 4; ++w) {
      const float ov = red_v[w][tid];
      const int   oi = red_i[w][tid];
      if (ov < v || (ov == v && oi < i)) { v = ov; i = oi; }
    }
    win[tid] = i;
    idx_out[(size_t)(tok0 + tid) * Qq + q] = (float)i;   // indices as float
  }
  __syncthreads();

  // epilogue: gather winner codeword, loss, residual & qout update.
  //   e = q - r; q_st = r + e; r_new = r - q_st; qout += q_st; loss += e^2
  float lsum = 0.0f;
  {
    const float4* cb4   = reinterpret_cast<const float4*>(cb);
    float4* routp = reinterpret_cast<float4*>(rout + (size_t)tok0 * Dd);
    float4* qoutp = reinterpret_cast<float4*>(qout + (size_t)tok0 * Dd);
#pragma unroll
    for (int k = 0; k < (TT * Dd / 4) / NT; ++k) {
      const int j  = tid + k * NT;
      const int m  = j >> 6;        // wave-uniform token
      const int d4 = j & 63;
      const int widx = win[m];
      const float4 cv = cb4[(size_t)widx * (Dd / 4) + d4];
      const float4 rv = rs[m][d4];
      const float ex = cv.x - rv.x, ey = cv.y - rv.y, ez = cv.z - rv.z, ew = cv.w - rv.w;
      const float qsx = rv.x + ex, qsy = rv.y + ey, qsz = rv.z + ez, qsw = rv.w + ew;
      lsum += ex * ex + ey * ey + ez * ez + ew * ew;
      routp[j] = make_float4(rv.x - qsx, rv.y - qsy, rv.z - qsz, rv.w - qsw);
      float4 qo;
      if (q == 0) {
        qo = make_float4(qsx, qsy, qsz, qsw);            // overwrite (no stale state)
      } else {
        const float4 old = qoutp[j];
        qo = make_float4(old.x + qsx, old.y + qsy, old.z + qsz, old.w + qsw);
      }
      qoutp[j] = qo;
    }
  }
#pragma unroll
  for (int s = 32; s; s >>= 1) lsum += __shfl_xor(lsum, s);
  if (lane == 0) atomicAdd(&loss_acc[q], lsum);
}

// ---------------------------------------------------------------------------
__global__ void finalize_losses(const float* __restrict__ loss_acc,
                                float* __restrict__ loss_out) {
  if (threadIdx.x < Qq) loss_out[threadIdx.x] = loss_acc[threadIdx.x] * (1.0f / (float)(Mm * Dd));
}

extern "C" void kernel_launch(void* const* d_in, const int* in_sizes, int n_in,
                              void* d_out, int out_size, void* d_ws, size_t ws_size,
                              hipStream_t stream) {
  const float* x   = (const float*)d_in[0];   // [B,N,D]
  const float* cbs = (const float*)d_in[1];   // [Q,C,D]
  float* out      = (float*)d_out;
  float* qout     = out;                               // M*D
  float* idx_out  = out + (size_t)Mm * Dd;             // M*Q
  float* loss_out = idx_out + (size_t)Mm * Qq;         // Q

  float* residual = (float*)d_ws;                      // M*D floats = 32 MB
  float* loss_acc = residual + (size_t)Mm * Dd;        // 64 floats
  float* cnorm    = loss_acc + 64;                     // Q*C floats
  float4* cbT     = reinterpret_cast<float4*>(cnorm + (size_t)Qq * Cc);  // Q*(D/4)*C float4 = 8 MB

  prep_kernel<<<(Qq * Cc) / 4, NT, 0, stream>>>(cbs, cnorm, loss_acc);
  transpose_cb<<<Qq * (Cc / TC), NT, 0, stream>>>(cbs, cbT);

  for (int q = 0; q < Qq; ++q) {
    const float* rin = (q == 0) ? x : residual;
    vq_stage<<<Mm / TT, NT, 0, stream>>>(cbs + (size_t)q * Cc * Dd,
                                         cbT + (size_t)q * (Dd / 4) * Cc,
                                         cnorm + (size_t)q * Cc,
                                         rin, residual,
                                         qout, idx_out, loss_acc, q);
  }

  finalize_losses<<<1, 64, 0, stream>>>(loss_acc, loss_out);
}